// Round 24
// baseline (214.770 us; speedup 1.0000x reference)
//
#include <hip/hip_runtime.h>
#include <math.h>

#define N_NODES 100000
#define N_EDGES 3200000
#define BSHIFT 8
#define NPB 256                 // nodes per bucket = 1<<BSHIFT
#define BMASK (NPB - 1)
#define NB 391                  // ceil(N_NODES / NPB)
#define CAP 10240               // bucket capacity (mean 8192, +22 sigma)
#define STG_BLOCKS 512          // stage half (scheduled first)
#define FC1_BLOCKS 2048         // fc1 half
#define NTILES 6250             // N_NODES/16
#define STG_PER 6252            // edges per stage block, multiple of 4

typedef __attribute__((ext_vector_type(8))) short short8v;   // 8 bf16 = 4 VGPR
typedef __attribute__((ext_vector_type(4))) float f32x4;     // MFMA C/D
typedef __attribute__((address_space(3))) unsigned lds_u32;
typedef const __attribute__((address_space(1))) unsigned glb_u32;

__device__ inline unsigned cvt_pk_bf16(float a, float b) {
  unsigned r;
  asm("v_cvt_pk_bf16_f32 %0, %1, %2" : "=v"(r) : "v"(a), "v"(b));
  return r;
}
__device__ inline unsigned short f32_to_bf16(float f) {
  union { float f; unsigned u; } v; v.f = f;
  unsigned r = v.u + 0x7fff + ((v.u >> 16) & 1);   // RNE
  return (unsigned short)(r >> 16);
}
__device__ inline float bf16_to_f32(unsigned short h) {
  union { unsigned u; float f; } v; v.u = ((unsigned)h) << 16;
  return v.f;
}

// Issue one K-half (16 rows x 1KB) of tile tl into buffer bufsel (async).
#define ISSUE(tl, ch, bufsel)                                              \
  {                                                                        \
    const float* xb_ = x + (size_t)(tl) * 8192 + (ch) * 256;               \
    char* dst_ = smem + (bufsel) * 16384;                                  \
    _Pragma("unroll") for (int i_ = 0; i_ < 4; ++i_) {                     \
      const int r_ = wib * 4 + i_;                                         \
      const int gb_ = (lane * 16) ^ ((r_ & 7) << 5);                       \
      __builtin_amdgcn_global_load_lds(                                    \
          (glb_u32*)(xb_ + r_ * 512 + (gb_ >> 2)),                         \
          (lds_u32*)(dst_ + r_ * 1024), 16, 0, 0);                         \
    }                                                                      \
  }
// Compute this wave's 2 K-steps of chunk ch from buffer bufsel.
#define COMPUTE(ch, bufsel)                                                \
  {                                                                        \
    const char* bb_ = smem + (bufsel) * 16384;                             \
    _Pragma("unroll") for (int u_ = 0; u_ < 2; ++u_) {                     \
      const int ls_ = wib * 2 + u_;                                        \
      const int cb_ = (ls_ * 128 + kb * 32) ^ ((o & 7) << 5);              \
      const char* p_ = bb_ + o * 1024 + cb_;                               \
      const float4 a0_ = *(const float4*)p_;                               \
      const float4 a1_ = *(const float4*)(p_ + 16);                        \
      union { unsigned u[4]; short8v v; } fa_;                             \
      fa_.u[0] = cvt_pk_bf16(a0_.x, a0_.y);                                \
      fa_.u[1] = cvt_pk_bf16(a0_.z, a0_.w);                                \
      fa_.u[2] = cvt_pk_bf16(a1_.x, a1_.y);                                \
      fa_.u[3] = cvt_pk_bf16(a1_.z, a1_.w);                                \
      c4 = __builtin_amdgcn_mfma_f32_16x16x32_bf16(                        \
          fa_.v, wlds[(ch) * 8 + ls_][lane], c4, 0, 0, 0);                 \
    }                                                                      \
  }

// ---------------------------------------------------------------------------
// Fused stage ∥ fc1  [R23 + T3/T4 counted-vmcnt pipeline in fc1].
// stage (blocks [0,512)): int4-vectorized bucket scatter.
// fc1 (blocks [512,2560)): tile split into two 16KB K-halves, double-
// buffered. Chunk c+1's async global_load_lds issue BEFORE computing chunk
// c; wait with counted s_waitcnt vmcnt(4) (next chunk's 4 loads stay in
// flight) + RAW s_barrier (no vmcnt(0) drain -- R20's __syncthreads ate
// ~900cy/tile). Explicit lgkmcnt(0) before the pbuf-read barrier.
// ---------------------------------------------------------------------------
__global__ __launch_bounds__(256) void fc1_stage_kernel(
    const float* __restrict__ x, const float* __restrict__ w,
    const float* __restrict__ b, unsigned short* __restrict__ h1,
    const int* __restrict__ src, const int* __restrict__ dst,
    int* __restrict__ gcur, int* __restrict__ staged) {
  __shared__ __align__(16) char smem[53248];  // 2x16KB bufs + 16KB wlds + 4KB pbuf

  if (blockIdx.x >= STG_BLOCKS) {
    // ---------------- fc1 ----------------
    short8v (*wlds)[64] = (short8v(*)[64])(smem + 32768);    // [16][64]
    f32x4* pbuf = (f32x4*)(smem + 49152);                    // [256]
    const int tid = threadIdx.x;
    const int lane = tid & 63;
    const int wib = tid >> 6;
    const int o = lane & 15;
    const int kb = lane >> 4;

    // Weight prologue: coalesced copy into buf area (32KB scratch) -> pack.
    float* scratch = (float*)smem;
    for (int i = tid; i < 2048; i += 256)
      ((float4*)scratch)[i] = ((const float4*)w)[i];
    __syncthreads();
    unsigned wpk[16];
    for (int idx = tid, n = 0; idx < 4096; idx += 256, ++n) {
      const int s = idx >> 8, ln = (idx >> 2) & 63, j = idx & 3;
      const int lkb = ln >> 4, lo = ln & 15;
      const int k = s * 32 + lkb * 8 + 2 * j;
      wpk[n] = cvt_pk_bf16(scratch[k * 16 + lo], scratch[(k + 1) * 16 + lo]);
    }
    __syncthreads();
    for (int idx = tid, n = 0; idx < 4096; idx += 256, ++n) {
      ((unsigned*)wlds)[idx] = wpk[n];
    }
    __syncthreads();

    const float bias = b[o];
    const int fcb = blockIdx.x - STG_BLOCKS;   // 0..2047
    int cur = 0;
    int t = fcb;
    if (t < NTILES) ISSUE(t, 0, cur);          // prologue: first chunk0

    for (; t < NTILES; t += FC1_BLOCKS) {
      f32x4 c4 = {0.f, 0.f, 0.f, 0.f};
      // ---- chunk 0 (in buf cur); chunk 1 loads into 1-cur ----
      ISSUE(t, 1, 1 - cur);
      asm volatile("s_waitcnt vmcnt(4)" ::: "memory");
      __builtin_amdgcn_sched_barrier(0);
      __builtin_amdgcn_s_barrier();
      COMPUTE(0, cur);
      __builtin_amdgcn_s_barrier();   // all reads of buf cur done
      cur ^= 1;
      // ---- chunk 1 (in buf cur); next tile's chunk0 into 1-cur ----
      const int tn = t + FC1_BLOCKS;
      if (tn < NTILES) {
        ISSUE(tn, 0, 1 - cur);
        asm volatile("s_waitcnt vmcnt(4)" ::: "memory");
      } else {
        asm volatile("s_waitcnt vmcnt(0)" ::: "memory");
      }
      __builtin_amdgcn_sched_barrier(0);
      __builtin_amdgcn_s_barrier();
      COMPUTE(1, cur);
      // ---- reduce partial C across waves, wave0 stores ----
      pbuf[wib * 64 + lane] = c4;
      asm volatile("s_waitcnt lgkmcnt(0)" ::: "memory");
      __builtin_amdgcn_s_barrier();
      if (wib == 0) {
        const f32x4 p0 = pbuf[lane];
        const f32x4 p1 = pbuf[64 + lane];
        const f32x4 p2 = pbuf[128 + lane];
        const f32x4 p3 = pbuf[192 + lane];
        const int rbase = t * 16 + (lane >> 4) * 4;
#pragma unroll
        for (int j = 0; j < 4; ++j) {
          const float vj = (p0[j] + p1[j]) + (p2[j] + p3[j]);
          h1[(size_t)(rbase + j) * 16 + o] =
              f32_to_bf16(fmaxf(vj + bias, 0.f));
        }
      }
      cur ^= 1;
    }
  } else {
    // ---------------- stage (int4-vectorized) ----------------
    int* hist = (int*)smem;
    int* base = (int*)(smem + 2048);
    const int tid = threadIdx.x;
    for (int i = tid; i < NB; i += 256) hist[i] = 0;
    __syncthreads();

    const int sb = blockIdx.x;
    const int e0 = sb * STG_PER;
    const int e1 = min(e0 + STG_PER, N_EDGES);
    const int em = e0 + ((e1 - e0) & ~3);

    for (int e = e0 + tid * 4; e < em; e += 1024) {
      const int4 d4 = *(const int4*)(dst + e);
      atomicAdd(&hist[d4.x >> BSHIFT], 1);
      atomicAdd(&hist[d4.y >> BSHIFT], 1);
      atomicAdd(&hist[d4.z >> BSHIFT], 1);
      atomicAdd(&hist[d4.w >> BSHIFT], 1);
    }
    for (int e = em + tid; e < e1; e += 256) {
      atomicAdd(&hist[dst[e] >> BSHIFT], 1);
    }
    __syncthreads();
    for (int bkt = tid; bkt < NB; bkt += 256) {
      int h = hist[bkt];
      base[bkt] = (h > 0) ? atomicAdd(&gcur[bkt], h) : 0;
      hist[bkt] = 0;
    }
    __syncthreads();
    for (int e = e0 + tid * 4; e < em; e += 1024) {
      const int4 d4 = *(const int4*)(dst + e);
      const int4 s4 = *(const int4*)(src + e);
      int bkt, pos;
      bkt = d4.x >> BSHIFT;
      pos = base[bkt] + atomicAdd(&hist[bkt], 1);
      if (pos < CAP) staged[bkt * CAP + pos] = (s4.x << 8) | (d4.x & BMASK);
      bkt = d4.y >> BSHIFT;
      pos = base[bkt] + atomicAdd(&hist[bkt], 1);
      if (pos < CAP) staged[bkt * CAP + pos] = (s4.y << 8) | (d4.y & BMASK);
      bkt = d4.z >> BSHIFT;
      pos = base[bkt] + atomicAdd(&hist[bkt], 1);
      if (pos < CAP) staged[bkt * CAP + pos] = (s4.z << 8) | (d4.z & BMASK);
      bkt = d4.w >> BSHIFT;
      pos = base[bkt] + atomicAdd(&hist[bkt], 1);
      if (pos < CAP) staged[bkt * CAP + pos] = (s4.w << 8) | (d4.w & BMASK);
    }
    for (int e = em + tid; e < e1; e += 256) {
      const int d = dst[e];
      const int s = src[e];
      const int bkt = d >> BSHIFT;
      const int pos = base[bkt] + atomicAdd(&hist[bkt], 1);
      if (pos < CAP) staged[bkt * CAP + pos] = (s << 8) | (d & BMASK);
    }
  }
}

// ---------------------------------------------------------------------------
// finalize: per bucket, LDS-sort staged slice by local dst; offs/cnt out.
// ---------------------------------------------------------------------------
__global__ __launch_bounds__(256) void finalize_kernel(
    int* __restrict__ staged, const int* __restrict__ gcur,
    int* __restrict__ offs, int* __restrict__ cnt) {
  __shared__ int ed[CAP];
  __shared__ int lcnt[NPB];
  __shared__ int lofs[NPB];
  __shared__ int sc[256];
  const int bkt = blockIdx.x, tid = threadIdx.x;
  const int nE = min(gcur[bkt], CAP);
  const int base = bkt * CAP;
  for (int e = tid; e < nE; e += 256) ed[e] = staged[base + e];
  lcnt[tid] = 0;
  __syncthreads();
  for (int e = tid; e < nE; e += 256) atomicAdd(&lcnt[ed[e] & BMASK], 1);
  __syncthreads();
  const int v = lcnt[tid];
  sc[tid] = v;
  __syncthreads();
  for (int d = 1; d < 256; d <<= 1) {
    int add = (tid >= d) ? sc[tid - d] : 0;
    __syncthreads();
    sc[tid] += add;
    __syncthreads();
  }
  const int excl = sc[tid] - v;
  lofs[tid] = excl;
  const int g = bkt * NPB + tid;
  if (g < N_NODES) {
    offs[g] = base + excl;
    cnt[g] = v;
  }
  lcnt[tid] = 0;  // reuse as cursor
  __syncthreads();
  for (int e = tid; e < nE; e += 256) {
    int u = ed[e];
    int dl = u & BMASK;
    int pos = lofs[dl] + atomicAdd(&lcnt[dl], 1);
    staged[base + pos] = u >> 8;  // plain src index, node-sorted
  }
}

// ---------------------------------------------------------------------------
// conv1 (16 -> 32): 8 threads/node, 4-deep unrolled bf16 gather (8B/lane,
// 32B/row -> L2-resident h1). Weight LDS swizzled: store quad Q of row k at
// Q^(k>>2); read original quad q from 4*(q^t), accumulate into p[q].
// ---------------------------------------------------------------------------
__global__ __launch_bounds__(256) void conv1_kernel(
    const unsigned short* __restrict__ h1, const int* __restrict__ csr,
    const int* __restrict__ offs, const int* __restrict__ cnt,
    const float* __restrict__ llw, const float* __restrict__ llb,
    const float* __restrict__ lrw, const float* __restrict__ c2llw,
    float* __restrict__ h2, unsigned short* __restrict__ t2) {
  __shared__ float wl[512], wr[512], w2c[512];
  __shared__ float bb[32];
  for (int idx = threadIdx.x; idx < 512; idx += 256) {
    const int k = idx >> 5, jj = idx & 31;
    const int sj = 4 * ((jj >> 2) ^ (k >> 2)) + (jj & 3);  // swizzle store
    wl[k * 32 + sj] = llw[idx];
    wr[k * 32 + sj] = lrw[idx];
    w2c[idx] = c2llw[idx];  // unswizzled
  }
  if (threadIdx.x < 32) bb[threadIdx.x] = llb[threadIdx.x];
  __syncthreads();

  const int tid = blockIdx.x * 256 + threadIdx.x;
  const int i = tid >> 3;
  if (i >= N_NODES) return;
  const int t8 = threadIdx.x & 7;
  const int gg = t8 >> 2;       // group 0/1
  const int t = t8 & 3;         // dim slice
  const int start = offs[i], deg = cnt[i];

  float4 acc = make_float4(0.f, 0.f, 0.f, 0.f);
  int e = gg;
  for (; e + 6 < deg; e += 8) {
    const int s0 = csr[start + e];
    const int s1 = csr[start + e + 2];
    const int s2 = csr[start + e + 4];
    const int s3 = csr[start + e + 6];
    ushort4 a0 = *(const ushort4*)(h1 + (size_t)s0 * 16 + t * 4);
    ushort4 a1 = *(const ushort4*)(h1 + (size_t)s1 * 16 + t * 4);
    ushort4 a2 = *(const ushort4*)(h1 + (size_t)s2 * 16 + t * 4);
    ushort4 a3 = *(const ushort4*)(h1 + (size_t)s3 * 16 + t * 4);
    acc.x += (bf16_to_f32(a0.x) + bf16_to_f32(a1.x)) +
             (bf16_to_f32(a2.x) + bf16_to_f32(a3.x));
    acc.y += (bf16_to_f32(a0.y) + bf16_to_f32(a1.y)) +
             (bf16_to_f32(a2.y) + bf16_to_f32(a3.y));
    acc.z += (bf16_to_f32(a0.z) + bf16_to_f32(a1.z)) +
             (bf16_to_f32(a2.z) + bf16_to_f32(a3.z));
    acc.w += (bf16_to_f32(a0.w) + bf16_to_f32(a1.w)) +
             (bf16_to_f32(a2.w) + bf16_to_f32(a3.w));
  }
  for (; e < deg; e += 2) {
    const int s = csr[start + e];
    ushort4 a = *(const ushort4*)(h1 + (size_t)s * 16 + t * 4);
    acc.x += bf16_to_f32(a.x); acc.y += bf16_to_f32(a.y);
    acc.z += bf16_to_f32(a.z); acc.w += bf16_to_f32(a.w);
  }
  acc.x += __shfl_xor(acc.x, 4, 64);
  acc.y += __shfl_xor(acc.y, 4, 64);
  acc.z += __shfl_xor(acc.z, 4, 64);
  acc.w += __shfl_xor(acc.w, 4, 64);

  const float inv = 1.f / (float)(deg > 0 ? deg : 1);
  const ushort4 selfu = *(const ushort4*)(h1 + (size_t)i * 16 + t * 4);
  const float mk[4] = {acc.x * inv, acc.y * inv, acc.z * inv, acc.w * inv};
  const float sk[4] = {bf16_to_f32(selfu.x), bf16_to_f32(selfu.y),
                       bf16_to_f32(selfu.z), bf16_to_f32(selfu.w)};

  float4 p[8];
#pragma unroll
  for (int q = 0; q < 8; ++q) p[q] = make_float4(0.f, 0.f, 0.f, 0.f);
#pragma unroll
  for (int j = 0; j < 4; ++j) {
    const int k = 4 * t + j;          // k>>2 == t
#pragma unroll
    for (int q = 0; q < 8; ++q) {
      const int qs = 4 * (q ^ t);     // swizzled position of original quad q
      float4 w4l = *(const float4*)&wl[k * 32 + qs];
      float4 w4r = *(const float4*)&wr[k * 32 + qs];
      p[q].x += mk[j] * w4l.x + sk[j] * w4r.x;
      p[q].y += mk[j] * w4l.y + sk[j] * w4r.y;
      p[q].z += mk[j] * w4l.z + sk[j] * w4r.z;
      p[q].w += mk[j] * w4l.w + sk[j] * w4r.w;
    }
  }
#pragma unroll
  for (int mask = 1; mask <= 2; mask <<= 1) {
#pragma unroll
    for (int q = 0; q < 8; ++q) {
      p[q].x += __shfl_xor(p[q].x, mask, 64);
      p[q].y += __shfl_xor(p[q].y, mask, 64);
      p[q].z += __shfl_xor(p[q].z, mask, 64);
      p[q].w += __shfl_xor(p[q].w, mask, 64);
    }
  }
  float o[32];
#pragma unroll
  for (int q = 0; q < 8; ++q) {
    o[4 * q + 0] = fmaxf(p[q].x + bb[4 * q + 0], 0.f);
    o[4 * q + 1] = fmaxf(p[q].y + bb[4 * q + 1], 0.f);
    o[4 * q + 2] = fmaxf(p[q].z + bb[4 * q + 2], 0.f);
    o[4 * q + 3] = fmaxf(p[q].w + bb[4 * q + 3], 0.f);
  }
  *(float4*)(h2 + (size_t)i * 32 + 4 * t8) =
      make_float4(o[4 * t8], o[4 * t8 + 1], o[4 * t8 + 2], o[4 * t8 + 3]);
  float t0 = 0.f, t1 = 0.f;
#pragma unroll
  for (int k = 0; k < 32; ++k) {
    const float ok = o[k];
    t0 += ok * w2c[k * 16 + 2 * t8];
    t1 += ok * w2c[k * 16 + 2 * t8 + 1];
  }
  *(unsigned*)(t2 + (size_t)i * 16 + 2 * t8) = cvt_pk_bf16(t0, t1);
}

// ---------------------------------------------------------------------------
// conv2 (pre-transformed bf16 t2, 16-dim agg) + fc2 + head -> d_out.
// ---------------------------------------------------------------------------
__global__ __launch_bounds__(256) void conv2_kernel(
    const unsigned short* __restrict__ t2, const float* __restrict__ h2,
    const int* __restrict__ csr, const int* __restrict__ offs,
    const int* __restrict__ cnt, const float* __restrict__ llb,
    const float* __restrict__ lrw, const float* __restrict__ fc2w,
    const float* __restrict__ fc2b, float* __restrict__ out) {
  __shared__ float wr[512];
  __shared__ float bb[16];
  __shared__ float w2[48];
  __shared__ float b2[3];
  for (int idx = threadIdx.x; idx < 512; idx += 256) {
    const int k = idx >> 4, jj = idx & 15;
    const int sj = 4 * ((jj >> 2) ^ ((k >> 2) & 3)) + (jj & 3);  // swizzle
    wr[k * 16 + sj] = lrw[idx];
  }
  if (threadIdx.x < 16) bb[threadIdx.x] = llb[threadIdx.x];
  else if (threadIdx.x >= 64 && threadIdx.x < 112) w2[threadIdx.x - 64] = fc2w[threadIdx.x - 64];
  else if (threadIdx.x >= 128 && threadIdx.x < 131) b2[threadIdx.x - 128] = fc2b[threadIdx.x - 128];
  __syncthreads();

  const int tid = blockIdx.x * 256 + threadIdx.x;
  const int i = tid >> 3;
  if (i >= N_NODES) return;
  const int t8 = threadIdx.x & 7;
  const int gg = t8 >> 2;
  const int t = t8 & 3;
  const int start = offs[i], deg = cnt[i];

  float4 acc = make_float4(0.f, 0.f, 0.f, 0.f);
  int e = gg;
  for (; e + 6 < deg; e += 8) {
    const int s0 = csr[start + e];
    const int s1 = csr[start + e + 2];
    const int s2 = csr[start + e + 4];
    const int s3 = csr[start + e + 6];
    ushort4 a0 = *(const ushort4*)(t2 + (size_t)s0 * 16 + t * 4);
    ushort4 a1 = *(const ushort4*)(t2 + (size_t)s1 * 16 + t * 4);
    ushort4 a2 = *(const ushort4*)(t2 + (size_t)s2 * 16 + t * 4);
    ushort4 a3 = *(const ushort4*)(t2 + (size_t)s3 * 16 + t * 4);
    acc.x += (bf16_to_f32(a0.x) + bf16_to_f32(a1.x)) +
             (bf16_to_f32(a2.x) + bf16_to_f32(a3.x));
    acc.y += (bf16_to_f32(a0.y) + bf16_to_f32(a1.y)) +
             (bf16_to_f32(a2.y) + bf16_to_f32(a3.y));
    acc.z += (bf16_to_f32(a0.z) + bf16_to_f32(a1.z)) +
             (bf16_to_f32(a2.z) + bf16_to_f32(a3.z));
    acc.w += (bf16_to_f32(a0.w) + bf16_to_f32(a1.w)) +
             (bf16_to_f32(a2.w) + bf16_to_f32(a3.w));
  }
  for (; e < deg; e += 2) {
    const int s = csr[start + e];
    ushort4 a = *(const ushort4*)(t2 + (size_t)s * 16 + t * 4);
    acc.x += bf16_to_f32(a.x); acc.y += bf16_to_f32(a.y);
    acc.z += bf16_to_f32(a.z); acc.w += bf16_to_f32(a.w);
  }
  acc.x += __shfl_xor(acc.x, 4, 64);
  acc.y += __shfl_xor(acc.y, 4, 64);
  acc.z += __shfl_xor(acc.z, 4, 64);
  acc.w += __shfl_xor(acc.w, 4, 64);

  const float inv = 1.f / (float)(deg > 0 ? deg : 1);
  const float4 s0v = *(const float4*)(h2 + (size_t)i * 32 + 4 * t8);
  const float sk[4] = {s0v.x, s0v.y, s0v.z, s0v.w};
  float4 p[4];
#pragma unroll
  for (int q = 0; q < 4; ++q) p[q] = make_float4(0.f, 0.f, 0.f, 0.f);
#pragma unroll
  for (int kk = 0; kk < 4; ++kk) {
    const int k = 4 * t8 + kk;        // (k>>2)&3 == t8&3
    const float s = sk[kk];
#pragma unroll
    for (int q = 0; q < 4; ++q) {
      const int qs = 4 * (q ^ (t8 & 3));  // swizzled position of quad q
      const float4 wv = *(const float4*)&wr[k * 16 + qs];
      p[q].x += s * wv.x; p[q].y += s * wv.y;
      p[q].z += s * wv.z; p[q].w += s * wv.w;
    }
  }
  if (gg == 0) {
    p[t].x += acc.x * inv; p[t].y += acc.y * inv;
    p[t].z += acc.z * inv; p[t].w += acc.w * inv;
  }
#pragma unroll
  for (int mask = 1; mask <= 4; mask <<= 1) {
#pragma unroll
    for (int q = 0; q < 4; ++q) {
      p[q].x += __shfl_xor(p[q].x, mask, 64);
      p[q].y += __shfl_xor(p[q].y, mask, 64);
      p[q].z += __shfl_xor(p[q].z, mask, 64);
      p[q].w += __shfl_xor(p[q].w, mask, 64);
    }
  }
  if (t8 < 3) {
    float f[16];
#pragma unroll
    for (int q = 0; q < 4; ++q) {
      f[4 * q + 0] = fmaxf(p[q].x + bb[4 * q + 0], 0.f);
      f[4 * q + 1] = fmaxf(p[q].y + bb[4 * q + 1], 0.f);
      f[4 * q + 2] = fmaxf(p[q].z + bb[4 * q + 2], 0.f);
      f[4 * q + 3] = fmaxf(p[q].w + bb[4 * q + 3], 0.f);
    }
    float v0 = b2[0], v1 = b2[1], v2 = b2[2];
#pragma unroll
    for (int k = 0; k < 16; ++k) {
      v0 += f[k] * w2[k * 3 + 0];
      v1 += f[k] * w2[k * 3 + 1];
      v2 += f[k] * w2[k * 3 + 2];
    }
    float gsi = 1.f / (1.f + expf(-v1));
    float mxi = 1.f / (1.f + expf(-v2));
    float fsi = fmaxf(v0, 0.f) + gsi;
    float rv = (t8 == 0) ? fsi : ((t8 == 1) ? gsi : mxi);
    out[(size_t)i * 3 + t8] = rv;
  }
}

extern "C" void kernel_launch(void* const* d_in, const int* in_sizes, int n_in,
                              void* d_out, int out_size, void* d_ws, size_t ws_size,
                              hipStream_t stream) {
  const float* x = (const float*)d_in[0];
  const int* ei = (const int*)d_in[1];
  const float* fc1w = (const float*)d_in[2];
  const float* fc1b = (const float*)d_in[3];
  const float* c1llw = (const float*)d_in[4];
  const float* c1llb = (const float*)d_in[5];
  const float* c1lrw = (const float*)d_in[6];
  const float* c2llw = (const float*)d_in[7];
  const float* c2llb = (const float*)d_in[8];
  const float* c2lrw = (const float*)d_in[9];
  const float* fc2w = (const float*)d_in[10];
  const float* fc2b = (const float*)d_in[11];
  float* outp = (float*)d_out;
  const int* src = ei;
  const int* dst = ei + N_EDGES;

  char* ws = (char*)d_ws;
  unsigned short* h1 = (unsigned short*)ws;  ws += (size_t)N_NODES * 16 * 2;
  float* h2 = (float*)ws;                    ws += (size_t)N_NODES * 32 * 4;
  unsigned short* t2 = (unsigned short*)ws;  ws += (size_t)N_NODES * 16 * 2;
  int* staged = (int*)ws;                    ws += (size_t)NB * CAP * 4;
  int* gcur = (int*)ws;                      ws += (size_t)NB * 4;
  int* offs = (int*)ws;                      ws += (size_t)N_NODES * 4;
  int* cnt = (int*)ws;                       ws += (size_t)N_NODES * 4;
  (void)ws_size; (void)n_in; (void)in_sizes; (void)out_size;

  hipMemsetAsync(gcur, 0, (size_t)NB * 4, stream);
  fc1_stage_kernel<<<STG_BLOCKS + FC1_BLOCKS, 256, 0, stream>>>(
      x, fc1w, fc1b, h1, src, dst, gcur, staged);
  finalize_kernel<<<NB, 256, 0, stream>>>(staged, gcur, offs, cnt);
  conv1_kernel<<<(N_NODES * 8 + 255) / 256, 256, 0, stream>>>(
      h1, staged, offs, cnt, c1llw, c1llb, c1lrw, c2llw, h2, t2);
  conv2_kernel<<<(N_NODES * 8 + 255) / 256, 256, 0, stream>>>(
      t2, h2, staged, offs, cnt, c2llb, c2lrw, fc2w, fc2b, outp);
}

// Round 25
// 203.066 us; speedup vs baseline: 1.0576x; 1.0576x over previous
//
#include <hip/hip_runtime.h>
#include <math.h>

#define N_NODES 100000
#define N_EDGES 3200000
#define BSHIFT 8
#define NPB 256                 // nodes per bucket = 1<<BSHIFT
#define BMASK (NPB - 1)
#define NB 391                  // ceil(N_NODES / NPB)
#define CAP 10240               // bucket capacity (mean 8192, +22 sigma)
#define STG_BLOCKS 768          // stage half (rebalanced 512->768)
#define FC1_BLOCKS 1792         // fc1 half (2048->1792)
#define NTILES 6250             // N_NODES/16
#define STG_PER 4168            // edges per stage block, multiple of 4

typedef __attribute__((ext_vector_type(8))) short short8v;   // 8 bf16 = 4 VGPR
typedef __attribute__((ext_vector_type(4))) float f32x4;     // MFMA C/D
typedef __attribute__((address_space(3))) unsigned lds_u32;
typedef const __attribute__((address_space(1))) unsigned glb_u32;

__device__ inline unsigned cvt_pk_bf16(float a, float b) {
  unsigned r;
  asm("v_cvt_pk_bf16_f32 %0, %1, %2" : "=v"(r) : "v"(a), "v"(b));
  return r;
}
__device__ inline unsigned short f32_to_bf16(float f) {
  union { float f; unsigned u; } v; v.f = f;
  unsigned r = v.u + 0x7fff + ((v.u >> 16) & 1);   // RNE
  return (unsigned short)(r >> 16);
}
__device__ inline float bf16_to_f32(unsigned short h) {
  union { unsigned u; float f; } v; v.u = ((unsigned)h) << 16;
  return v.f;
}

// ---------------------------------------------------------------------------
// Fused stage ∥ fc1  [R23 body = best known; only the block ratio changed
// this round to probe which half binds the ~125us kernel].
// stage (blocks [0,768)): int4-vectorized bucket scatter.
// fc1 (blocks [768,2560)): MFMA 16x16x32 bf16 with async global_load_lds
// staging (width=16, zero VGPR round-trip); source pre-swizzled
// (off ^ (row&7)<<5) so linear LDS writes give a bank-spread layout.
// K split across 4 waves; partial-C reduced via LDS; wave 0 stores h1.
// ---------------------------------------------------------------------------
__global__ __launch_bounds__(256) void fc1_stage_kernel(
    const float* __restrict__ x, const float* __restrict__ w,
    const float* __restrict__ b, unsigned short* __restrict__ h1,
    const int* __restrict__ src, const int* __restrict__ dst,
    int* __restrict__ gcur, int* __restrict__ staged) {
  __shared__ __align__(16) char smem[53248];   // 32KB tile + 16KB wfrags + 4KB pbuf

  if (blockIdx.x >= STG_BLOCKS) {
    // ---------------- fc1 ----------------
    float* tile = (float*)smem;                              // [16][512] f32
    short8v (*wlds)[64] = (short8v(*)[64])(smem + 32768);    // [16][64]
    f32x4* pbuf = (f32x4*)(smem + 49152);                    // [256]
    const int tid = threadIdx.x;
    const int lane = tid & 63;
    const int wib = tid >> 6;
    const int o = lane & 15;
    const int kb = lane >> 4;

    // Weight prologue: coalesced copy into tile scratch, then pack frags.
    for (int i = tid; i < 2048; i += 256)
      ((float4*)tile)[i] = ((const float4*)w)[i];
    __syncthreads();
    for (int idx = tid; idx < 4096; idx += 256) {
      const int s = idx >> 8, ln = (idx >> 2) & 63, j = idx & 3;
      const int lkb = ln >> 4, lo = ln & 15;
      const int k = s * 32 + lkb * 8 + 2 * j;
      ((unsigned*)&wlds[s][ln])[j] =
          cvt_pk_bf16(tile[k * 16 + lo], tile[(k + 1) * 16 + lo]);
    }
    __syncthreads();

    const float bias = b[o];
    const int fcb = blockIdx.x - STG_BLOCKS;   // 0..1791

    for (int tileid = fcb; tileid < NTILES; tileid += FC1_BLOCKS) {
      const float* xbase = x + (size_t)tileid * 8192;   // 16 rows x 512
      // Issue 8 async 1KB wave-loads per wave (chunks wib*8..wib*8+7).
#pragma unroll
      for (int i = 0; i < 8; ++i) {
        const int c = wib * 8 + i;
        const int r = c >> 1;                       // row 0..15
        const int off = (c & 1) * 1024 + lane * 16; // physical byte in row
        const int goff = off ^ ((r & 7) << 5);      // pre-swizzled source
        __builtin_amdgcn_global_load_lds(
            (glb_u32*)(xbase + r * 512 + (goff >> 2)),
            (lds_u32*)((char*)tile + (size_t)c * 1024 + lane * 16) - lane * 4,
            16, 0, 0);
      }
      __syncthreads();   // drains vmcnt -> tile ready

      // Compute: wave wib handles K-steps s = wib*4 .. wib*4+3.
      f32x4 c4 = {0.f, 0.f, 0.f, 0.f};
#pragma unroll
      for (int ss = 0; ss < 4; ++ss) {
        const int s = wib * 4 + ss;
        const int cb = (s * 128 + kb * 32) ^ ((o & 7) << 5);
        const char* p = (const char*)tile + o * 2048 + cb;
        const float4 a0 = *(const float4*)p;
        const float4 a1 = *(const float4*)(p + 16);
        union { unsigned u[4]; short8v v; } fa;
        fa.u[0] = cvt_pk_bf16(a0.x, a0.y);
        fa.u[1] = cvt_pk_bf16(a0.z, a0.w);
        fa.u[2] = cvt_pk_bf16(a1.x, a1.y);
        fa.u[3] = cvt_pk_bf16(a1.z, a1.w);
        c4 = __builtin_amdgcn_mfma_f32_16x16x32_bf16(fa.v, wlds[s][lane], c4,
                                                     0, 0, 0);
      }
      pbuf[wib * 64 + lane] = c4;
      __syncthreads();
      if (wib == 0) {
        const f32x4 p0 = pbuf[lane];
        const f32x4 p1 = pbuf[64 + lane];
        const f32x4 p2 = pbuf[128 + lane];
        const f32x4 p3 = pbuf[192 + lane];
        const int rbase = tileid * 16 + (lane >> 4) * 4;
#pragma unroll
        for (int j = 0; j < 4; ++j) {
          const float vj = (p0[j] + p1[j]) + (p2[j] + p3[j]);
          h1[(size_t)(rbase + j) * 16 + o] =
              f32_to_bf16(fmaxf(vj + bias, 0.f));
        }
      }
      __syncthreads();   // protect tile before next round's async loads
    }
  } else {
    // ---------------- stage (int4-vectorized) ----------------
    int* hist = (int*)smem;
    int* base = (int*)(smem + 2048);
    const int tid = threadIdx.x;
    for (int i = tid; i < NB; i += 256) hist[i] = 0;
    __syncthreads();

    const int sb = blockIdx.x;
    const int e0 = sb * STG_PER;                 // multiple of 4 -> aligned
    const int e1 = min(e0 + STG_PER, N_EDGES);
    if (e0 < N_EDGES) {
      const int em = e0 + ((e1 - e0) & ~3);      // vector-loop end

      // pass 1: histogram
      for (int e = e0 + tid * 4; e < em; e += 1024) {
        const int4 d4 = *(const int4*)(dst + e);
        atomicAdd(&hist[d4.x >> BSHIFT], 1);
        atomicAdd(&hist[d4.y >> BSHIFT], 1);
        atomicAdd(&hist[d4.z >> BSHIFT], 1);
        atomicAdd(&hist[d4.w >> BSHIFT], 1);
      }
      for (int e = em + tid; e < e1; e += 256) {
        atomicAdd(&hist[dst[e] >> BSHIFT], 1);
      }
      __syncthreads();
      for (int bkt = tid; bkt < NB; bkt += 256) {
        int h = hist[bkt];
        base[bkt] = (h > 0) ? atomicAdd(&gcur[bkt], h) : 0;
        hist[bkt] = 0;  // reuse as local cursor
      }
      __syncthreads();
      // pass 2: scatter
      for (int e = e0 + tid * 4; e < em; e += 1024) {
        const int4 d4 = *(const int4*)(dst + e);
        const int4 s4 = *(const int4*)(src + e);
        int bkt, pos;
        bkt = d4.x >> BSHIFT;
        pos = base[bkt] + atomicAdd(&hist[bkt], 1);
        if (pos < CAP) staged[bkt * CAP + pos] = (s4.x << 8) | (d4.x & BMASK);
        bkt = d4.y >> BSHIFT;
        pos = base[bkt] + atomicAdd(&hist[bkt], 1);
        if (pos < CAP) staged[bkt * CAP + pos] = (s4.y << 8) | (d4.y & BMASK);
        bkt = d4.z >> BSHIFT;
        pos = base[bkt] + atomicAdd(&hist[bkt], 1);
        if (pos < CAP) staged[bkt * CAP + pos] = (s4.z << 8) | (d4.z & BMASK);
        bkt = d4.w >> BSHIFT;
        pos = base[bkt] + atomicAdd(&hist[bkt], 1);
        if (pos < CAP) staged[bkt * CAP + pos] = (s4.w << 8) | (d4.w & BMASK);
      }
      for (int e = em + tid; e < e1; e += 256) {
        const int d = dst[e];
        const int s = src[e];
        const int bkt = d >> BSHIFT;
        const int pos = base[bkt] + atomicAdd(&hist[bkt], 1);
        if (pos < CAP) staged[bkt * CAP + pos] = (s << 8) | (d & BMASK);
      }
    }
  }
}

// ---------------------------------------------------------------------------
// finalize: per bucket, LDS-sort staged slice by local dst; offs/cnt out.
// ---------------------------------------------------------------------------
__global__ __launch_bounds__(256) void finalize_kernel(
    int* __restrict__ staged, const int* __restrict__ gcur,
    int* __restrict__ offs, int* __restrict__ cnt) {
  __shared__ int ed[CAP];
  __shared__ int lcnt[NPB];
  __shared__ int lofs[NPB];
  __shared__ int sc[256];
  const int bkt = blockIdx.x, tid = threadIdx.x;
  const int nE = min(gcur[bkt], CAP);
  const int base = bkt * CAP;
  for (int e = tid; e < nE; e += 256) ed[e] = staged[base + e];
  lcnt[tid] = 0;
  __syncthreads();
  for (int e = tid; e < nE; e += 256) atomicAdd(&lcnt[ed[e] & BMASK], 1);
  __syncthreads();
  const int v = lcnt[tid];
  sc[tid] = v;
  __syncthreads();
  for (int d = 1; d < 256; d <<= 1) {
    int add = (tid >= d) ? sc[tid - d] : 0;
    __syncthreads();
    sc[tid] += add;
    __syncthreads();
  }
  const int excl = sc[tid] - v;
  lofs[tid] = excl;
  const int g = bkt * NPB + tid;
  if (g < N_NODES) {
    offs[g] = base + excl;
    cnt[g] = v;
  }
  lcnt[tid] = 0;  // reuse as cursor
  __syncthreads();
  for (int e = tid; e < nE; e += 256) {
    int u = ed[e];
    int dl = u & BMASK;
    int pos = lofs[dl] + atomicAdd(&lcnt[dl], 1);
    staged[base + pos] = u >> 8;  // plain src index, node-sorted
  }
}

// ---------------------------------------------------------------------------
// conv1 (16 -> 32): 8 threads/node, 4-deep unrolled bf16 gather (8B/lane,
// 32B/row -> L2-resident h1). Weight LDS swizzled: store quad Q of row k at
// Q^(k>>2); read original quad q from 4*(q^t), accumulate into p[q].
// ---------------------------------------------------------------------------
__global__ __launch_bounds__(256) void conv1_kernel(
    const unsigned short* __restrict__ h1, const int* __restrict__ csr,
    const int* __restrict__ offs, const int* __restrict__ cnt,
    const float* __restrict__ llw, const float* __restrict__ llb,
    const float* __restrict__ lrw, const float* __restrict__ c2llw,
    float* __restrict__ h2, unsigned short* __restrict__ t2) {
  __shared__ float wl[512], wr[512], w2c[512];
  __shared__ float bb[32];
  for (int idx = threadIdx.x; idx < 512; idx += 256) {
    const int k = idx >> 5, jj = idx & 31;
    const int sj = 4 * ((jj >> 2) ^ (k >> 2)) + (jj & 3);  // swizzle store
    wl[k * 32 + sj] = llw[idx];
    wr[k * 32 + sj] = lrw[idx];
    w2c[idx] = c2llw[idx];  // unswizzled
  }
  if (threadIdx.x < 32) bb[threadIdx.x] = llb[threadIdx.x];
  __syncthreads();

  const int tid = blockIdx.x * 256 + threadIdx.x;
  const int i = tid >> 3;
  if (i >= N_NODES) return;
  const int t8 = threadIdx.x & 7;
  const int gg = t8 >> 2;       // group 0/1
  const int t = t8 & 3;         // dim slice
  const int start = offs[i], deg = cnt[i];

  float4 acc = make_float4(0.f, 0.f, 0.f, 0.f);
  int e = gg;
  for (; e + 6 < deg; e += 8) {
    const int s0 = csr[start + e];
    const int s1 = csr[start + e + 2];
    const int s2 = csr[start + e + 4];
    const int s3 = csr[start + e + 6];
    ushort4 a0 = *(const ushort4*)(h1 + (size_t)s0 * 16 + t * 4);
    ushort4 a1 = *(const ushort4*)(h1 + (size_t)s1 * 16 + t * 4);
    ushort4 a2 = *(const ushort4*)(h1 + (size_t)s2 * 16 + t * 4);
    ushort4 a3 = *(const ushort4*)(h1 + (size_t)s3 * 16 + t * 4);
    acc.x += (bf16_to_f32(a0.x) + bf16_to_f32(a1.x)) +
             (bf16_to_f32(a2.x) + bf16_to_f32(a3.x));
    acc.y += (bf16_to_f32(a0.y) + bf16_to_f32(a1.y)) +
             (bf16_to_f32(a2.y) + bf16_to_f32(a3.y));
    acc.z += (bf16_to_f32(a0.z) + bf16_to_f32(a1.z)) +
             (bf16_to_f32(a2.z) + bf16_to_f32(a3.z));
    acc.w += (bf16_to_f32(a0.w) + bf16_to_f32(a1.w)) +
             (bf16_to_f32(a2.w) + bf16_to_f32(a3.w));
  }
  for (; e < deg; e += 2) {
    const int s = csr[start + e];
    ushort4 a = *(const ushort4*)(h1 + (size_t)s * 16 + t * 4);
    acc.x += bf16_to_f32(a.x); acc.y += bf16_to_f32(a.y);
    acc.z += bf16_to_f32(a.z); acc.w += bf16_to_f32(a.w);
  }
  acc.x += __shfl_xor(acc.x, 4, 64);
  acc.y += __shfl_xor(acc.y, 4, 64);
  acc.z += __shfl_xor(acc.z, 4, 64);
  acc.w += __shfl_xor(acc.w, 4, 64);

  const float inv = 1.f / (float)(deg > 0 ? deg : 1);
  const ushort4 selfu = *(const ushort4*)(h1 + (size_t)i * 16 + t * 4);
  const float mk[4] = {acc.x * inv, acc.y * inv, acc.z * inv, acc.w * inv};
  const float sk[4] = {bf16_to_f32(selfu.x), bf16_to_f32(selfu.y),
                       bf16_to_f32(selfu.z), bf16_to_f32(selfu.w)};

  float4 p[8];
#pragma unroll
  for (int q = 0; q < 8; ++q) p[q] = make_float4(0.f, 0.f, 0.f, 0.f);
#pragma unroll
  for (int j = 0; j < 4; ++j) {
    const int k = 4 * t + j;          // k>>2 == t
#pragma unroll
    for (int q = 0; q < 8; ++q) {
      const int qs = 4 * (q ^ t);     // swizzled position of original quad q
      float4 w4l = *(const float4*)&wl[k * 32 + qs];
      float4 w4r = *(const float4*)&wr[k * 32 + qs];
      p[q].x += mk[j] * w4l.x + sk[j] * w4r.x;
      p[q].y += mk[j] * w4l.y + sk[j] * w4r.y;
      p[q].z += mk[j] * w4l.z + sk[j] * w4r.z;
      p[q].w += mk[j] * w4l.w + sk[j] * w4r.w;
    }
  }
#pragma unroll
  for (int mask = 1; mask <= 2; mask <<= 1) {
#pragma unroll
    for (int q = 0; q < 8; ++q) {
      p[q].x += __shfl_xor(p[q].x, mask, 64);
      p[q].y += __shfl_xor(p[q].y, mask, 64);
      p[q].z += __shfl_xor(p[q].z, mask, 64);
      p[q].w += __shfl_xor(p[q].w, mask, 64);
    }
  }
  float o[32];
#pragma unroll
  for (int q = 0; q < 8; ++q) {
    o[4 * q + 0] = fmaxf(p[q].x + bb[4 * q + 0], 0.f);
    o[4 * q + 1] = fmaxf(p[q].y + bb[4 * q + 1], 0.f);
    o[4 * q + 2] = fmaxf(p[q].z + bb[4 * q + 2], 0.f);
    o[4 * q + 3] = fmaxf(p[q].w + bb[4 * q + 3], 0.f);
  }
  *(float4*)(h2 + (size_t)i * 32 + 4 * t8) =
      make_float4(o[4 * t8], o[4 * t8 + 1], o[4 * t8 + 2], o[4 * t8 + 3]);
  float t0 = 0.f, t1 = 0.f;
#pragma unroll
  for (int k = 0; k < 32; ++k) {
    const float ok = o[k];
    t0 += ok * w2c[k * 16 + 2 * t8];
    t1 += ok * w2c[k * 16 + 2 * t8 + 1];
  }
  *(unsigned*)(t2 + (size_t)i * 16 + 2 * t8) = cvt_pk_bf16(t0, t1);
}

// ---------------------------------------------------------------------------
// conv2 (pre-transformed bf16 t2, 16-dim agg) + fc2 + head -> d_out.
// ---------------------------------------------------------------------------
__global__ __launch_bounds__(256) void conv2_kernel(
    const unsigned short* __restrict__ t2, const float* __restrict__ h2,
    const int* __restrict__ csr, const int* __restrict__ offs,
    const int* __restrict__ cnt, const float* __restrict__ llb,
    const float* __restrict__ lrw, const float* __restrict__ fc2w,
    const float* __restrict__ fc2b, float* __restrict__ out) {
  __shared__ float wr[512];
  __shared__ float bb[16];
  __shared__ float w2[48];
  __shared__ float b2[3];
  for (int idx = threadIdx.x; idx < 512; idx += 256) {
    const int k = idx >> 4, jj = idx & 15;
    const int sj = 4 * ((jj >> 2) ^ ((k >> 2) & 3)) + (jj & 3);  // swizzle
    wr[k * 16 + sj] = lrw[idx];
  }
  if (threadIdx.x < 16) bb[threadIdx.x] = llb[threadIdx.x];
  else if (threadIdx.x >= 64 && threadIdx.x < 112) w2[threadIdx.x - 64] = fc2w[threadIdx.x - 64];
  else if (threadIdx.x >= 128 && threadIdx.x < 131) b2[threadIdx.x - 128] = fc2b[threadIdx.x - 128];
  __syncthreads();

  const int tid = blockIdx.x * 256 + threadIdx.x;
  const int i = tid >> 3;
  if (i >= N_NODES) return;
  const int t8 = threadIdx.x & 7;
  const int gg = t8 >> 2;
  const int t = t8 & 3;
  const int start = offs[i], deg = cnt[i];

  float4 acc = make_float4(0.f, 0.f, 0.f, 0.f);
  int e = gg;
  for (; e + 6 < deg; e += 8) {
    const int s0 = csr[start + e];
    const int s1 = csr[start + e + 2];
    const int s2 = csr[start + e + 4];
    const int s3 = csr[start + e + 6];
    ushort4 a0 = *(const ushort4*)(t2 + (size_t)s0 * 16 + t * 4);
    ushort4 a1 = *(const ushort4*)(t2 + (size_t)s1 * 16 + t * 4);
    ushort4 a2 = *(const ushort4*)(t2 + (size_t)s2 * 16 + t * 4);
    ushort4 a3 = *(const ushort4*)(t2 + (size_t)s3 * 16 + t * 4);
    acc.x += (bf16_to_f32(a0.x) + bf16_to_f32(a1.x)) +
             (bf16_to_f32(a2.x) + bf16_to_f32(a3.x));
    acc.y += (bf16_to_f32(a0.y) + bf16_to_f32(a1.y)) +
             (bf16_to_f32(a2.y) + bf16_to_f32(a3.y));
    acc.z += (bf16_to_f32(a0.z) + bf16_to_f32(a1.z)) +
             (bf16_to_f32(a2.z) + bf16_to_f32(a3.z));
    acc.w += (bf16_to_f32(a0.w) + bf16_to_f32(a1.w)) +
             (bf16_to_f32(a2.w) + bf16_to_f32(a3.w));
  }
  for (; e < deg; e += 2) {
    const int s = csr[start + e];
    ushort4 a = *(const ushort4*)(t2 + (size_t)s * 16 + t * 4);
    acc.x += bf16_to_f32(a.x); acc.y += bf16_to_f32(a.y);
    acc.z += bf16_to_f32(a.z); acc.w += bf16_to_f32(a.w);
  }
  acc.x += __shfl_xor(acc.x, 4, 64);
  acc.y += __shfl_xor(acc.y, 4, 64);
  acc.z += __shfl_xor(acc.z, 4, 64);
  acc.w += __shfl_xor(acc.w, 4, 64);

  const float inv = 1.f / (float)(deg > 0 ? deg : 1);
  const float4 s0v = *(const float4*)(h2 + (size_t)i * 32 + 4 * t8);
  const float sk[4] = {s0v.x, s0v.y, s0v.z, s0v.w};
  float4 p[4];
#pragma unroll
  for (int q = 0; q < 4; ++q) p[q] = make_float4(0.f, 0.f, 0.f, 0.f);
#pragma unroll
  for (int kk = 0; kk < 4; ++kk) {
    const int k = 4 * t8 + kk;        // (k>>2)&3 == t8&3
    const float s = sk[kk];
#pragma unroll
    for (int q = 0; q < 4; ++q) {
      const int qs = 4 * (q ^ (t8 & 3));  // swizzled position of quad q
      const float4 wv = *(const float4*)&wr[k * 16 + qs];
      p[q].x += s * wv.x; p[q].y += s * wv.y;
      p[q].z += s * wv.z; p[q].w += s * wv.w;
    }
  }
  if (gg == 0) {
    p[t].x += acc.x * inv; p[t].y += acc.y * inv;
    p[t].z += acc.z * inv; p[t].w += acc.w * inv;
  }
#pragma unroll
  for (int mask = 1; mask <= 4; mask <<= 1) {
#pragma unroll
    for (int q = 0; q < 4; ++q) {
      p[q].x += __shfl_xor(p[q].x, mask, 64);
      p[q].y += __shfl_xor(p[q].y, mask, 64);
      p[q].z += __shfl_xor(p[q].z, mask, 64);
      p[q].w += __shfl_xor(p[q].w, mask, 64);
    }
  }
  if (t8 < 3) {
    float f[16];
#pragma unroll
    for (int q = 0; q < 4; ++q) {
      f[4 * q + 0] = fmaxf(p[q].x + bb[4 * q + 0], 0.f);
      f[4 * q + 1] = fmaxf(p[q].y + bb[4 * q + 1], 0.f);
      f[4 * q + 2] = fmaxf(p[q].z + bb[4 * q + 2], 0.f);
      f[4 * q + 3] = fmaxf(p[q].w + bb[4 * q + 3], 0.f);
    }
    float v0 = b2[0], v1 = b2[1], v2 = b2[2];
#pragma unroll
    for (int k = 0; k < 16; ++k) {
      v0 += f[k] * w2[k * 3 + 0];
      v1 += f[k] * w2[k * 3 + 1];
      v2 += f[k] * w2[k * 3 + 2];
    }
    float gsi = 1.f / (1.f + expf(-v1));
    float mxi = 1.f / (1.f + expf(-v2));
    float fsi = fmaxf(v0, 0.f) + gsi;
    float rv = (t8 == 0) ? fsi : ((t8 == 1) ? gsi : mxi);
    out[(size_t)i * 3 + t8] = rv;
  }
}

extern "C" void kernel_launch(void* const* d_in, const int* in_sizes, int n_in,
                              void* d_out, int out_size, void* d_ws, size_t ws_size,
                              hipStream_t stream) {
  const float* x = (const float*)d_in[0];
  const int* ei = (const int*)d_in[1];
  const float* fc1w = (const float*)d_in[2];
  const float* fc1b = (const float*)d_in[3];
  const float* c1llw = (const float*)d_in[4];
  const float* c1llb = (const float*)d_in[5];
  const float* c1lrw = (const float*)d_in[6];
  const float* c2llw = (const float*)d_in[7];
  const float* c2llb = (const float*)d_in[8];
  const float* c2lrw = (const float*)d_in[9];
  const float* fc2w = (const float*)d_in[10];
  const float* fc2b = (const float*)d_in[11];
  float* outp = (float*)d_out;
  const int* src = ei;
  const int* dst = ei + N_EDGES;

  char* ws = (char*)d_ws;
  unsigned short* h1 = (unsigned short*)ws;  ws += (size_t)N_NODES * 16 * 2;
  float* h2 = (float*)ws;                    ws += (size_t)N_NODES * 32 * 4;
  unsigned short* t2 = (unsigned short*)ws;  ws += (size_t)N_NODES * 16 * 2;
  int* staged = (int*)ws;                    ws += (size_t)NB * CAP * 4;
  int* gcur = (int*)ws;                      ws += (size_t)NB * 4;
  int* offs = (int*)ws;                      ws += (size_t)N_NODES * 4;
  int* cnt = (int*)ws;                       ws += (size_t)N_NODES * 4;
  (void)ws_size; (void)n_in; (void)in_sizes; (void)out_size;

  hipMemsetAsync(gcur, 0, (size_t)NB * 4, stream);
  fc1_stage_kernel<<<STG_BLOCKS + FC1_BLOCKS, 256, 0, stream>>>(
      x, fc1w, fc1b, h1, src, dst, gcur, staged);
  finalize_kernel<<<NB, 256, 0, stream>>>(staged, gcur, offs, cnt);
  conv1_kernel<<<(N_NODES * 8 + 255) / 256, 256, 0, stream>>>(
      h1, staged, offs, cnt, c1llw, c1llb, c1lrw, c2llw, h2, t2);
  conv2_kernel<<<(N_NODES * 8 + 255) / 256, 256, 0, stream>>>(
      t2, h2, staged, offs, cnt, c2llb, c2lrw, fc2w, fc2b, outp);
}